// Round 4
// baseline (214.656 us; speedup 1.0000x reference)
//
#include <hip/hip_runtime.h>
#include <hip/hip_bf16.h>

typedef __hip_bfloat16 bf16;
typedef __attribute__((ext_vector_type(8))) short bf16x8;
typedef __attribute__((ext_vector_type(4))) float f32x4;

#define NNODE 512
#define NEDGE 16384
#define INLEN 17929
#define K1P   1088   // 1056 real cols zero-padded to 17*64 for BK=64 GEMM

// ---- workspace layout (offsets in floats) ----
#define WS_EA      0         // 16384
#define WS_CSRC    16384     // 16384 (int)
#define WS_CEA     32768     // 16384
#define WS_DEG     49152     // 512 (int)
#define WS_STARTS  49664     // 512 (int)
#define WS_LATTR   50176     // 512
#define WS_MM      50688     // 2
#define WS_MMP     50690     // 128
#define WS_STOPV   50818     // 512
#define WS_AE      51330     // 16
#define WS_PS      51346     // 4096
#define WS_G2WT    186624    // 256*256 (g2W transposed)
#define WS_Y       317696    // 512*256 (raw layer-2 aggregate, pre-W2)
#define WS_ASRC    448768    // 512*8
#define WS_ADST    452864    // 512*8
#define WS_UV      456960    // 512*64
#define WS_K       489728    // 512
#define WS_APACK   490240    // bf16 512*1088 -> 278528 floats
#define WS_BPACK   768768    // bf16 512*1088 -> 278528 floats
#define WS_X1      1047296   // f32 512*256 (layer-1 output X1)
#define WS_WC2B    1178368   // bf16 512*512  -> 131072 floats
#define WS_WESF    1309440   // 64*256
#define WS_ASRC2   1325824   // 512*8
#define WS_ADST2   1329920   // 512*8
#define WS_CURSOR  1334016   // 512 (int)
#define WS_DEGP    1334528   // 64*512 (int)
#define WS_LSUMP   1367296   // 64*512
#define WS_OUT1F   1400064   // f32 512*512 -> 262144 (split-K accumulator)
// end = 1662208 floats ~= 6.65 MB

static __device__ __forceinline__ unsigned short f2bfbits(float x){
  bf16 b = __float2bfloat16(x);
  union { bf16 b; unsigned short u; } c; c.b = b; return c.u;
}

// ============ K1: fused prep (all input-only, fully parallel) ===============
__global__ __launch_bounds__(256)
void k_prep(const float* __restrict__ demand, const float* __restrict__ W1,
            const float* __restrict__ att_s, const float* __restrict__ att_d,
            const int* __restrict__ stops, const float* __restrict__ Wes,
            const float* __restrict__ dist, const float* __restrict__ markov,
            const int* __restrict__ eidx,
            const float* __restrict__ g1We, const float* __restrict__ g1ae,
            const float* __restrict__ g2We, const float* __restrict__ g2ae,
            const float* __restrict__ g2W,  const float* __restrict__ g2as,
            const float* __restrict__ g2ad, const float* __restrict__ Wc2,
            float* __restrict__ outp, float* ws){
  int b = blockIdx.x, tid = threadIdx.x;
  if (b < 512){
    // layer-1 attention scalars (h is rank-1: h = demand[b]*W1)
    int hd = tid>>5, c = tid&31;
    float hv = demand[b] * W1[tid];
    float ps = hv * att_s[tid];
    float pd = hv * att_d[tid];
    for (int off=16; off; off>>=1){ ps += __shfl_down(ps,off,32); pd += __shfl_down(pd,off,32); }
    if (c==0){ ws[WS_ASRC + b*8+hd]=ps; ws[WS_ADST + b*8+hd]=pd; }
  } else if (b == 512){
    ws[WS_STOPV+tid] = 0.f; ws[WS_STOPV+256+tid] = 0.f;
    __syncthreads();
    ws[WS_STOPV + stops[tid]] = 1.0f;
    if (tid < 8){
      float s=0.f; for (int c=0;c<32;c++) s += g1We[tid*32+c]*g1ae[tid*32+c];
      ws[WS_AE+tid]=s;
    } else if (tid < 16){
      int h=tid-8; float s=0.f; for (int c=0;c<32;c++) s += g2We[h*32+c]*g2ae[h*32+c];
      ws[WS_AE+8+h]=s;
    }
  } else if (b < 515){
    for (int idx = (b-513)*8192 + tid; idx < (b-512)*8192; idx += 256){
      int k = idx>>8, c = idx&255;
      ws[WS_WESF+idx] = (k<32) ? Wes[k*512+c] : Wes[(k-32)*512+256+c];
    }
  } else if (b < 579){
    __shared__ float smn[256], smx[256];
    int p = b-515;
    float mn = 3.4e38f, mx = -3.4e38f;
    const float4* dv = (const float4*)(dist + p*4096);
    #pragma unroll
    for (int k=0;k<4;k++){
      float4 v = dv[k*256 + tid];
      mn = fminf(mn, fminf(fminf(v.x,v.y), fminf(v.z,v.w)));
      mx = fmaxf(mx, fmaxf(fmaxf(v.x,v.y), fmaxf(v.z,v.w)));
    }
    smn[tid]=mn; smx[tid]=mx; __syncthreads();
    for (int off=128; off; off>>=1){
      if (tid<off){ smn[tid]=fminf(smn[tid],smn[tid+off]); smx[tid]=fmaxf(smx[tid],smx[tid+off]); }
      __syncthreads();
    }
    if (tid==0){ ws[WS_MMP+p]=smn[0]; ws[WS_MMP+64+p]=smx[0]; }
  } else if (b < 643){
    // ea gather + per-block partial histogram (LDS, no global atomics)
    __shared__ int   hd_[512];
    __shared__ float hf_[512];
    int k = b-579;
    hd_[tid]=0; hd_[256+tid]=0; hf_[tid]=0.f; hf_[256+tid]=0.f;
    __syncthreads();
    int e = k*256 + tid;
    int r = eidx[e], c = eidx[NEDGE+e];
    float a = markov[r*NNODE + c];
    ws[WS_EA+e] = a;
    atomicAdd(&hd_[c], 1);
    atomicAdd(&hf_[c], a);
    __syncthreads();
    ((int*)(ws+WS_DEGP))[k*512+tid]     = hd_[tid];
    ((int*)(ws+WS_DEGP))[k*512+256+tid] = hd_[256+tid];
    ws[WS_LSUMP + k*512+tid]     = hf_[tid];
    ws[WS_LSUMP + k*512+256+tid] = hf_[256+tid];
  } else if (b < 659){
    int j = b-643;
    const float* att = (j<8) ? g2as : g2ad;
    int h = j&7;
    float s = 0.f;
    for (int c=0;c<32;c++) s += att[h*32+c] * g2W[(h*32+c)*256 + tid];
    ws[WS_PS + j*256 + tid] = s;
  } else if (b < 675){
    __shared__ float T[64][65];
    int tb = b-659, tr = tb>>2, tc = tb&3;
    int w = tid>>6, c = tid&63;
    for (int k=0;k<16;k++){
      int r = k*4 + w;
      T[r][c] = g2W[(tr*64+r)*256 + tc*64 + c];
    }
    __syncthreads();
    for (int k=0;k<16;k++){
      int r = k*4 + w;
      ws[WS_G2WT + (tc*64+r)*256 + tr*64 + c] = T[c][r];
    }
  } else if (b == 675){
    ((int*)(ws+WS_CURSOR))[tid] = 0;
    ((int*)(ws+WS_CURSOR))[256+tid] = 0;
  } else if (b < 740){
    // Wc2 -> bf16 pack (input-only)
    int blk = b - 676;
    const float4* src = (const float4*)(Wc2 + blk*4096);
    ushort4* dst = (ushort4*)((unsigned short*)(ws+WS_WC2B) + blk*4096);
    #pragma unroll
    for (int i=0;i<4;i++){
      float4 v = src[i*256+tid];
      ushort4 u;
      u.x = f2bfbits(v.x); u.y = f2bfbits(v.y);
      u.z = f2bfbits(v.z); u.w = f2bfbits(v.w);
      dst[i*256+tid] = u;
    }
  } else {
    // zero-init OUT1F + out (split-K atomic accumulators; ws/out poisoned)
    int blk = b - 740;
    float4 z = {0.f,0.f,0.f,0.f};
    float4* o1f = (float4*)(ws + WS_OUT1F);
    float4* op  = (float4*)outp;
    o1f[blk*512 + tid] = z;
    o1f[blk*512 + 256 + tid] = z;
    op[blk*512 + tid] = z;
    op[blk*512 + 256 + tid] = z;
  }
}

// ===== K2: scan + scatter — wave-shuffle scan (2 barriers, was 18) ==========
__global__ __launch_bounds__(512)
void k_scansc(const int* __restrict__ eidx, float* ws){
  __shared__ int startS[512];
  __shared__ int wsum[8];
  int t = threadIdx.x, b = blockIdx.x, lane = t&63, w = t>>6;
  const int* dp = (const int*)(ws+WS_DEGP);
  int d = 0;
  #pragma unroll 8
  for (int k=0;k<64;k++) d += dp[k*512+t];
  // inclusive wave scan
  int v = d;
  for (int off=1; off<64; off<<=1){
    int u = __shfl_up(v, off, 64);
    if (lane >= off) v += u;
  }
  if (lane==63) wsum[w] = v;
  __syncthreads();
  int base = 0;
  for (int k=0;k<w;k++) base += wsum[k];
  int incl = base + v;
  startS[t] = incl - d;
  if (b == 0){
    float l = 0.f;
    for (int k=0;k<64;k++) l += ws[WS_LSUMP+k*512+t];
    ((int*)(ws+WS_STARTS))[t] = incl - d;
    ((int*)(ws+WS_DEG))[t] = d;
    ws[WS_LATTR+t] = l / (float)(d>1 ? d : 1);
    if (t < 64){
      float mn = ws[WS_MMP+t], mx = ws[WS_MMP+64+t];
      for (int off=32; off; off>>=1){
        mn = fminf(mn, __shfl_down(mn,off,64));
        mx = fmaxf(mx, __shfl_down(mx,off,64));
      }
      if (t==0){ ws[WS_MM]=mn; ws[WS_MM+1]=mx; }
    }
  }
  __syncthreads();
  int e = b*512 + t;
  int c = eidx[NEDGE+e];
  int p = startS[c] + atomicAdd((int*)(ws+WS_CURSOR)+c, 1);
  ((int*)(ws+WS_CSRC))[p] = eidx[e];
  ws[WS_CEA+p] = ws[WS_EA+e];
}

// ============ GAT aggregate: CSR edges, single-pass softmax =================
// MODE1: rank-1 layer — aggregate demand scalars per head, X1 = relu(s*w1+b1),
//        + PS projections (ASRC2/ADST2). No 256-dim gather at all.
// MODE2: aggregate raw X1 rows into Y (W2 projection deferred to k_post).
template<int MODE>
__global__ __launch_bounds__(256)
void k_agg(const float* __restrict__ asrc, const float* __restrict__ adst,
           const float* __restrict__ AEp, const float* __restrict__ demand,
           const float* __restrict__ w1, const float* __restrict__ b1,
           float* ws){
  int t = blockIdx.x, tid = threadIdx.x, hd = tid>>5;
  __shared__ int   srcE[256];
  __shared__ float eaE[256];
  __shared__ float demE[256];
  __shared__ float Lall[256*8];
  __shared__ float AE[8], mh[8], dh[8], sw[8], sagg[8];
  __shared__ float xrow[256];
  if (tid<8) AE[tid]=AEp[tid];
  __syncthreads();
  const int* csrc = (const int*)(ws+WS_CSRC);
  const float* cea = ws+WS_CEA;
  int d  = ((const int*)(ws+WS_DEG))[t];
  int s0 = ((const int*)(ws+WS_STARTS))[t];
  if (d > 256) d = 256;
  for (int e=tid; e<d; e+=256){
    int s = csrc[s0+e];
    srcE[e]=s; eaE[e]=cea[s0+e];
    if (MODE==1) demE[e]=demand[s];
  }
  __syncthreads();
  {
    int h8 = tid&7;
    float adt = adst[t*8+h8], aeh = AE[h8];
    for (int e = tid>>3; e < d; e += 32){
      float a = asrc[srcE[e]*8+h8] + adt + eaE[e]*aeh;
      Lall[e*8+h8] = a>=0.f ? a : 0.2f*a;
    }
  }
  __syncthreads();
  {
    int h = tid>>5, j = tid&31;
    float aself = asrc[t*8+h] + adst[t*8+h] + ws[WS_LATTR+t]*AE[h];
    aself = aself>=0.f ? aself : 0.2f*aself;
    float mm = aself;
    for (int e=j; e<d; e+=32) mm = fmaxf(mm, Lall[e*8+h]);
    for (int off=16; off; off>>=1) mm = fmaxf(mm, __shfl_down(mm,off,32));
    mm = __shfl(mm, 0, 32);
    float dd = 0.f;
    for (int e=j; e<d; e+=32) dd += __expf(Lall[e*8+h]-mm);
    for (int off=16; off; off>>=1) dd += __shfl_down(dd,off,32);
    if (j==0){
      float se = __expf(aself-mm);
      mh[h]=mm; dh[h]=dd+se+1e-16f; sw[h]=se;
    }
  }
  __syncthreads();
  {
    int h8 = tid&7;
    for (int e = tid>>3; e < d; e += 32)
      Lall[e*8+h8] = __expf(Lall[e*8+h8] - mh[h8]);
  }
  __syncthreads();
  if (MODE == 1){
    // per-head scalar aggregation of demand
    int h = tid>>5, j = tid&31;
    float s = 0.f;
    for (int e=j; e<d; e+=32) s += Lall[e*8+h]*demE[e];
    for (int off=16; off; off>>=1) s += __shfl_down(s,off,32);
    if (j==0) sagg[h] = (s + sw[h]*demand[t]) / dh[h];
    __syncthreads();
    float v = fmaxf(sagg[hd]*w1[tid] + b1[tid], 0.f);
    xrow[tid] = v;
    ws[WS_X1 + t*256 + tid] = v;
    __syncthreads();
    if (tid < 64){
      int j2 = tid>>2, q = tid&3;
      const float* pr = ws + WS_PS + j2*256 + q*64;
      const float* xr = xrow + q*64;
      float p = 0.f;
      for (int c=0;c<64;c++) p += xr[c]*pr[c];
      p += __shfl_down(p,2,4);
      p += __shfl_down(p,1,4);
      if (q==0){
        if (j2<8) ws[WS_ASRC2 + t*8+j2] = p;
        else      ws[WS_ADST2 + t*8+(j2-8)] = p;
      }
    }
  } else {
    // aggregate raw X1 rows (8-way ILP); W2 projection deferred
    const float* x1 = ws + WS_X1;
    float a0 = sw[hd]*x1[t*256+tid], a1=0.f, a2=0.f, a3=0.f, a4=0.f, a5=0.f, a6=0.f, a7=0.f;
    int e = 0;
    for (; e+8<=d; e+=8){
      a0 += Lall[(e+0)*8+hd]*x1[srcE[e+0]*256+tid];
      a1 += Lall[(e+1)*8+hd]*x1[srcE[e+1]*256+tid];
      a2 += Lall[(e+2)*8+hd]*x1[srcE[e+2]*256+tid];
      a3 += Lall[(e+3)*8+hd]*x1[srcE[e+3]*256+tid];
      a4 += Lall[(e+4)*8+hd]*x1[srcE[e+4]*256+tid];
      a5 += Lall[(e+5)*8+hd]*x1[srcE[e+5]*256+tid];
      a6 += Lall[(e+6)*8+hd]*x1[srcE[e+6]*256+tid];
      a7 += Lall[(e+7)*8+hd]*x1[srcE[e+7]*256+tid];
    }
    for (; e<d; e++) a0 += Lall[e*8+hd]*x1[srcE[e]*256+tid];
    ws[WS_Y + t*256 + tid] = (((a0+a1)+(a2+a3))+((a4+a5)+(a6+a7)))/dh[hd];
  }
}

// ====== k_post: X2 = relu(Y@W2T + b2); UV = X2@WESF; APACK pack =============
// 128 blocks x 4 nodes: W2T/WESF tables read once per block (4x reuse).
__global__ __launch_bounds__(256)
void k_post(const float* __restrict__ dist, const float* __restrict__ markov,
            const float* __restrict__ g2b, float* ws){
  __shared__ float yls[4][256];
  __shared__ float o2[4][256];
  __shared__ float uvs[4][64];
  int b = blockIdx.x, tid = threadIdx.x, n0 = b*4;
  #pragma unroll
  for (int n=0;n<4;n++) yls[n][tid] = ws[WS_Y + (n0+n)*256 + tid];
  __syncthreads();
  const float* T = ws + WS_G2WT;
  float a0=0.f,a1=0.f,a2=0.f,a3=0.f;
  #pragma unroll 4
  for (int c=0;c<256;c++){
    float w = T[c*256+tid];
    a0 += yls[0][c]*w; a1 += yls[1][c]*w;
    a2 += yls[2][c]*w; a3 += yls[3][c]*w;
  }
  float bb = g2b[tid];
  o2[0][tid]=fmaxf(a0+bb,0.f); o2[1][tid]=fmaxf(a1+bb,0.f);
  o2[2][tid]=fmaxf(a2+bb,0.f); o2[3][tid]=fmaxf(a3+bb,0.f);
  __syncthreads();
  {
    int n = tid>>6, k = tid&63;
    const float* wk = ws + WS_WESF + k*256;
    float p = 0.f;
    #pragma unroll 4
    for (int c=0;c<256;c++) p += o2[n][c]*wk[c];
    uvs[n][k] = p;
    ws[WS_UV + (n0+n)*64 + k] = p;
  }
  __syncthreads();
  float mn = ws[WS_MM], mx = ws[WS_MM+1];
  float inv = 1.0f/(mx-mn);
  bf16* ap = (bf16*)(ws+WS_APACK);
  #pragma unroll
  for (int n=0;n<4;n++){
    int t = n0+n;
    const float* drow = dist + t*512;
    const float* mrow = markov + t*512;
    for (int j=tid; j<K1P; j+=256){
      float v2;
      if (j<32)        v2 = uvs[n][j];
      else if (j<544)  v2 = (drow[j-32] - mn) * inv;
      else if (j<1056) v2 = mrow[j-544];
      else             v2 = 0.f;   // zero-pad (ws is poisoned)
      ap[(size_t)t*K1P + j] = __float2bfloat16(v2);
    }
  }
}

// ====== K5: sk+packB — 1024 thr, wave-shuffle reductions (2 barriers) =======
__global__ __launch_bounds__(1024)
void k_skpack(const float* __restrict__ Wc1, const float* __restrict__ bc1,
              const float* __restrict__ bes, const float* __restrict__ Wweek,
              const float* __restrict__ Wcap, const float* __restrict__ Wveh,
              const int* __restrict__ wd, const int* __restrict__ vh,
              const int* __restrict__ cp, float* ws){
  int o = blockIdx.x, tid = threadIdx.x;
  __shared__ float besf[32];
  __shared__ float red[512];
  __shared__ float red2[16];
  if (tid<32) besf[tid] = bes[tid];
  __syncthreads();
  const float* wr = Wc1 + (size_t)o*INLEN;
  bf16* bp  = (bf16*)(ws+WS_BPACK);
  float be = besf[tid&31];
  const float* uvp = ws + WS_UV + ((tid>>5)<<6) + 32 + (tid&31);
  float sP = 0.f, tP0=0.f, tP1=0.f, tP2=0.f, tP3=0.f;
  #pragma unroll
  for (int i=0;i<16;i+=4){
    float w0 = wr[tid + 1024*(i+0)];
    float w1 = wr[tid + 1024*(i+1)];
    float w2 = wr[tid + 1024*(i+2)];
    float w3 = wr[tid + 1024*(i+3)];
    float u0 = uvp[2048*(i+0)];
    float u1 = uvp[2048*(i+1)];
    float u2 = uvp[2048*(i+2)];
    float u3 = uvp[2048*(i+3)];
    sP += (w0+w1)+(w2+w3);
    tP0 += w0*(u0+be);
    tP1 += w1*(u1+be);
    tP2 += w2*(u2+be);
    tP3 += w3*(u3+be);
  }
  float tP = (tP0+tP1)+(tP2+tP3);
  if (tid < 512) tP += ws[WS_STOPV+tid] * wr[17417+tid];
  if (tid < 9){
    int g = tid/3, f = tid-g*3;
    float sv = (g==0) ? Wweek[wd[0]*3+f]
             : (g==1) ? Wcap[cp[0]*3+f]
                      : Wveh[vh[0]*3+f];
    tP += sv * wr[17408+tid];
  }
  int lane = tid&63, w = tid>>6;
  sP += __shfl_down(sP, 32, 64);
  if (lane < 32) red[w*32 + lane] = sP;
  for (int off=32; off; off>>=1) tP += __shfl_down(tP, off, 64);
  if (lane == 0) red2[w] = tP;
  __syncthreads();
  if (tid < 32){
    float s = 0.f;
    #pragma unroll
    for (int k=0;k<16;k++) s += red[k*32+tid];
    bp[(size_t)o*K1P + tid] = __float2bfloat16(s);
    bp[(size_t)o*K1P + 1056 + tid] = __float2bfloat16(0.f);  // zero-pad
  } else if (tid == 32){
    float s = 0.f;
    #pragma unroll
    for (int k=0;k<16;k++) s += red2[k];
    ws[WS_K+o] = s + bc1[o];
  }
  bp[(size_t)o*K1P + 32 + tid] = __float2bfloat16(wr[16384+tid]);
}

// == gemm1: split-K bf16 MFMA, 64x64 tile, BK=64, 8 waves, f32 atomic out ====
__global__ __launch_bounds__(512)
void gemm1_splitk(const bf16* __restrict__ A, const bf16* __restrict__ B,
                  float* __restrict__ C, int N, int K){
  __shared__ short Als[2][4096];
  __shared__ short Bls[2][4096];
  const int tid = threadIdx.x;
  const int bm = blockIdx.y*64, bn = blockIdx.x*64;
  const int kz = blockIdx.z, NS = gridDim.z;
  const int nkT = K>>6;
  const int kb = (nkT*kz)/NS, ke = (nkT*(kz+1))/NS, cnt = ke-kb;
  const int wave = tid>>6, lane = tid&63;
  const int wm = wave>>2, wn = wave&3;
  const int r = lane&15, q = lane>>4;
  f32x4 acc[2] = {};
  const int lrow = tid>>3, lk8 = tid&7;
  const bf16* Ag = A + (size_t)(bm+lrow)*K + kb*64 + lk8*8;
  const bf16* Bg = B + (size_t)(bn+lrow)*K + kb*64 + lk8*8;
  const int sidx = ((lk8>>2)*256 + (lk8&3)*64 + lrow)*8;
  float4 av = *(const float4*)(Ag);
  float4 bv = *(const float4*)(Bg);
  *(float4*)(&Als[0][sidx]) = av;
  *(float4*)(&Bls[0][sidx]) = bv;
  __syncthreads();
  for (int kk=0; kk<cnt; kk++){
    int cur = kk&1, nxt = cur^1;
    if (kk+1 < cnt){
      av = *(const float4*)(Ag + (kk+1)*64);
      bv = *(const float4*)(Bg + (kk+1)*64);
    }
    #pragma unroll
    for (int k2=0; k2<2; k2++){
      bf16x8 bfr = *(const bf16x8*)(&Bls[cur][(k2*256 + q*64 + wn*16 + r)*8]);
      #pragma unroll
      for (int i=0;i<2;i++){
        bf16x8 af = *(const bf16x8*)(&Als[cur][(k2*256 + q*64 + wm*32 + i*16 + r)*8]);
        acc[i] = __builtin_amdgcn_mfma_f32_16x16x32_bf16(af, bfr, acc[i], 0,0,0);
      }
    }
    if (kk+1 < cnt){
      __syncthreads();
      *(float4*)(&Als[nxt][sidx]) = av;
      *(float4*)(&Bls[nxt][sidx]) = bv;
      __syncthreads();
    }
  }
  const int col = bn + wn*16 + r;
  #pragma unroll
  for (int i=0;i<2;i++){
    int row = bm + wm*32 + i*16 + q*4;
    #pragma unroll
    for (int g=0; g<4; g++)
      atomicAdd(&C[(size_t)(row+g)*N + col], acc[i][g]);
  }
}

// == gemm2: A = relu(OUT1F + K) converted to bf16 on the fly (ep1 merged) ====
__global__ __launch_bounds__(512)
void gemm2_f32a(const float* __restrict__ Af, const bf16* __restrict__ B,
                const float* __restrict__ kbias, const float* __restrict__ bc2,
                float* __restrict__ C){
  const int N = 512, K = 512;
  __shared__ short Als[2][4096];
  __shared__ short Bls[2][4096];
  const int tid = threadIdx.x;
  const int bm = blockIdx.y*64, bn = blockIdx.x*64;
  const int kz = blockIdx.z, NS = gridDim.z;
  const int nkT = K>>6;
  const int kb = (nkT*kz)/NS, ke = (nkT*(kz+1))/NS, cnt = ke-kb;
  const int wave = tid>>6, lane = tid&63;
  const int wm = wave>>2, wn = wave&3;
  const int r = lane&15, q = lane>>4;
  f32x4 acc[2] = {};
  const int lrow = tid>>3, lk8 = tid&7;
  const float* Ag = Af + (size_t)(bm+lrow)*K + kb*64 + lk8*8;
  const bf16*  Bg = B  + (size_t)(bn+lrow)*K + kb*64 + lk8*8;
  const float* Kg = kbias + kb*64 + lk8*8;
  const int sidx = ((lk8>>2)*256 + (lk8&3)*64 + lrow)*8;
  union PK { ushort u[8]; float4 f; };
  float4 x0, x1, k0, k1, bv;
  auto loadA = [&](int kk){
    x0 = *(const float4*)(Ag + kk*64);
    x1 = *(const float4*)(Ag + kk*64 + 4);
    k0 = *(const float4*)(Kg + kk*64);
    k1 = *(const float4*)(Kg + kk*64 + 4);
  };
  auto packA = [&]()->float4 {
    PK p;
    p.u[0]=f2bfbits(fmaxf(x0.x+k0.x,0.f));
    p.u[1]=f2bfbits(fmaxf(x0.y+k0.y,0.f));
    p.u[2]=f2bfbits(fmaxf(x0.z+k0.z,0.f));
    p.u[3]=f2bfbits(fmaxf(x0.w+k0.w,0.f));
    p.u[4]=f2bfbits(fmaxf(x1.x+k1.x,0.f));
    p.u[5]=f2bfbits(fmaxf(x1.y+k1.y,0.f));
    p.u[6]=f2bfbits(fmaxf(x1.z+k1.z,0.f));
    p.u[7]=f2bfbits(fmaxf(x1.w+k1.w,0.f));
    return p.f;
  };
  loadA(0);
  bv = *(const float4*)(Bg);
  *(float4*)(&Als[0][sidx]) = packA();
  *(float4*)(&Bls[0][sidx]) = bv;
  __syncthreads();
  for (int kk=0; kk<cnt; kk++){
    int cur = kk&1, nxt = cur^1;
    if (kk+1 < cnt){
      loadA(kk+1);
      bv = *(const float4*)(Bg + (kk+1)*64);
    }
    #pragma unroll
    for (int k2=0; k2<2; k2++){
      bf16x8 bfr = *(const bf16x8*)(&Bls[cur][(k2*256 + q*64 + wn*16 + r)*8]);
      #pragma unroll
      for (int i=0;i<2;i++){
        bf16x8 af = *(const bf16x8*)(&Als[cur][(k2*256 + q*64 + wm*32 + i*16 + r)*8]);
        acc[i] = __builtin_amdgcn_mfma_f32_16x16x32_bf16(af, bfr, acc[i], 0,0,0);
      }
    }
    if (kk+1 < cnt){
      __syncthreads();
      *(float4*)(&Als[nxt][sidx]) = packA();
      *(float4*)(&Bls[nxt][sidx]) = bv;
      __syncthreads();
    }
  }
  const int col = bn + wn*16 + r;
  const float bi = (kz==0) ? bc2[col] : 0.f;
  #pragma unroll
  for (int i=0;i<2;i++){
    int row = bm + wm*32 + i*16 + q*4;
    #pragma unroll
    for (int g=0; g<4; g++)
      atomicAdd(&C[(size_t)(row+g)*N + col], acc[i][g] + bi);
  }
}

extern "C" void kernel_launch(void* const* d_in, const int* in_sizes, int n_in,
                              void* d_out, int out_size, void* d_ws, size_t ws_size,
                              hipStream_t stream){
  const float* dist   = (const float*)d_in[0];
  const float* markov = (const float*)d_in[1];
  const float* demand = (const float*)d_in[2];
  const float* Wweek  = (const float*)d_in[3];
  const float* Wcap   = (const float*)d_in[4];
  const float* Wveh   = (const float*)d_in[5];
  const float* g1W    = (const float*)d_in[6];
  const float* g1as   = (const float*)d_in[7];
  const float* g1ad   = (const float*)d_in[8];
  const float* g1We   = (const float*)d_in[9];
  const float* g1ae   = (const float*)d_in[10];
  const float* g1b    = (const float*)d_in[11];
  const float* g2W    = (const float*)d_in[12];
  const float* g2as   = (const float*)d_in[13];
  const float* g2ad   = (const float*)d_in[14];
  const float* g2We   = (const float*)d_in[15];
  const float* g2ae   = (const float*)d_in[16];
  const float* g2b    = (const float*)d_in[17];
  const float* Wes    = (const float*)d_in[18];
  const float* bes    = (const float*)d_in[19];
  const float* Wc1    = (const float*)d_in[20];
  const float* bc1    = (const float*)d_in[21];
  const float* Wc2    = (const float*)d_in[22];
  const float* bc2    = (const float*)d_in[23];
  const int*   stops  = (const int*)d_in[24];
  const int*   eidx   = (const int*)d_in[25];
  const int*   wd     = (const int*)d_in[26];
  const int*   vh     = (const int*)d_in[27];
  const int*   cp     = (const int*)d_in[28];
  float* out = (float*)d_out;
  float* ws = (float*)d_ws;

  k_prep<<<868,256,0,stream>>>(demand, g1W, g1as, g1ad, stops, Wes, dist, markov, eidx,
                               g1We, g1ae, g2We, g2ae, g2W, g2as, g2ad, Wc2, out, ws);
  k_scansc<<<32,512,0,stream>>>(eidx, ws);
  k_agg<1><<<512,256,0,stream>>>(ws+WS_ASRC, ws+WS_ADST, ws+WS_AE, demand, g1W, g1b, ws);
  k_agg<2><<<512,256,0,stream>>>(ws+WS_ASRC2, ws+WS_ADST2, ws+WS_AE+8, demand, g1W, g1b, ws);
  k_post<<<128,256,0,stream>>>(dist, markov, g2b, ws);
  k_skpack<<<512,1024,0,stream>>>(Wc1, bc1, bes, Wweek, Wcap, Wveh, wd, vh, cp, ws);
  gemm1_splitk<<<dim3(8,8,4),512,0,stream>>>((const bf16*)(ws+WS_APACK), (const bf16*)(ws+WS_BPACK),
                                             ws+WS_OUT1F, 512, K1P);
  gemm2_f32a<<<dim3(8,8,2),512,0,stream>>>(ws+WS_OUT1F, (const bf16*)(ws+WS_WC2B),
                                           ws+WS_K, bc2, out);
}

// Round 6
// 191.305 us; speedup vs baseline: 1.1221x; 1.1221x over previous
//
#include <hip/hip_runtime.h>
#include <hip/hip_bf16.h>

typedef __hip_bfloat16 bf16;
typedef __attribute__((ext_vector_type(8))) short bf16x8;
typedef __attribute__((ext_vector_type(4))) float f32x4;

#define NNODE 512
#define NEDGE 16384
#define INLEN 17929
#define K1P   1088   // 1056 real cols zero-padded to 17*64 for BK=64 GEMM

// ---- workspace layout (offsets in floats) ----
#define WS_EA      0         // 16384
#define WS_CSRC    16384     // 16384 (int)
#define WS_CEA     32768     // 16384
#define WS_DEG     49152     // 512 (int)
#define WS_STARTS  49664     // 512 (int)
#define WS_LATTR   50176     // 512
#define WS_MM      50688     // 2
#define WS_MMP     50690     // 128
#define WS_STOPV   50818     // 512
#define WS_AE      51330     // 16
#define WS_PS      51346     // 4096
#define WS_G2WT    186624    // 256*256 (g2W transposed)
#define WS_H2      317696    // 512*256 (X1 @ W2^T rows)
#define WS_ASRC    448768    // 512*8
#define WS_ADST    452864    // 512*8
#define WS_UV      456960    // 512*64
#define WS_K       489728    // 512
#define WS_APACK   490240    // bf16 512*1088 -> 278528 floats
#define WS_BPACK   768768    // bf16 512*1088 -> 278528 floats
#define WS_OUT1    1047296   // bf16 512*512  -> 131072 floats
#define WS_WC2B    1178368   // bf16 512*512  -> 131072 floats
#define WS_WESF    1309440   // 64*256
#define WS_ASRC2   1325824   // 512*8
#define WS_ADST2   1329920   // 512*8
#define WS_CURSOR  1334016   // 512 (int)
#define WS_DEGP    1334528   // 64*512 (int)
#define WS_LSUMP   1367296   // 64*512
#define WS_OUT1F   1400064   // f32 512*512 -> 262144 (split-K accumulator)
// end = 1662208 floats ~= 6.65 MB

static __device__ __forceinline__ unsigned short f2bfbits(float x){
  bf16 b = __float2bfloat16(x);
  union { bf16 b; unsigned short u; } c; c.b = b; return c.u;
}

// ============ K1: fused prep (all input-only, fully parallel) ===============
__global__ __launch_bounds__(256)
void k_prep(const float* __restrict__ demand, const float* __restrict__ W1,
            const float* __restrict__ att_s, const float* __restrict__ att_d,
            const int* __restrict__ stops, const float* __restrict__ Wes,
            const float* __restrict__ dist, const float* __restrict__ markov,
            const int* __restrict__ eidx,
            const float* __restrict__ g1We, const float* __restrict__ g1ae,
            const float* __restrict__ g2We, const float* __restrict__ g2ae,
            const float* __restrict__ g2W,  const float* __restrict__ g2as,
            const float* __restrict__ g2ad, const float* __restrict__ Wc2,
            float* __restrict__ outp, float* ws){
  int b = blockIdx.x, tid = threadIdx.x;
  if (b < 512){
    // layer-1 attention scalars (h is rank-1: h = demand[b]*W1; no H store)
    int hd = tid>>5, c = tid&31;
    float hv = demand[b] * W1[tid];
    float ps = hv * att_s[tid];
    float pd = hv * att_d[tid];
    for (int off=16; off; off>>=1){ ps += __shfl_down(ps,off,32); pd += __shfl_down(pd,off,32); }
    if (c==0){ ws[WS_ASRC + b*8+hd]=ps; ws[WS_ADST + b*8+hd]=pd; }
  } else if (b == 512){
    ws[WS_STOPV+tid] = 0.f; ws[WS_STOPV+256+tid] = 0.f;
    __syncthreads();
    ws[WS_STOPV + stops[tid]] = 1.0f;
    if (tid < 8){
      float s=0.f; for (int c=0;c<32;c++) s += g1We[tid*32+c]*g1ae[tid*32+c];
      ws[WS_AE+tid]=s;
    } else if (tid < 16){
      int h=tid-8; float s=0.f; for (int c=0;c<32;c++) s += g2We[h*32+c]*g2ae[h*32+c];
      ws[WS_AE+8+h]=s;
    }
  } else if (b < 515){
    for (int idx = (b-513)*8192 + tid; idx < (b-512)*8192; idx += 256){
      int k = idx>>8, c = idx&255;
      ws[WS_WESF+idx] = (k<32) ? Wes[k*512+c] : Wes[(k-32)*512+256+c];
    }
  } else if (b < 579){
    __shared__ float smn[256], smx[256];
    int p = b-515;
    float mn = 3.4e38f, mx = -3.4e38f;
    const float4* dv = (const float4*)(dist + p*4096);
    #pragma unroll
    for (int k=0;k<4;k++){
      float4 v = dv[k*256 + tid];
      mn = fminf(mn, fminf(fminf(v.x,v.y), fminf(v.z,v.w)));
      mx = fmaxf(mx, fmaxf(fmaxf(v.x,v.y), fmaxf(v.z,v.w)));
    }
    smn[tid]=mn; smx[tid]=mx; __syncthreads();
    for (int off=128; off; off>>=1){
      if (tid<off){ smn[tid]=fminf(smn[tid],smn[tid+off]); smx[tid]=fmaxf(smx[tid],smx[tid+off]); }
      __syncthreads();
    }
    if (tid==0){ ws[WS_MMP+p]=smn[0]; ws[WS_MMP+64+p]=smx[0]; }
  } else if (b < 643){
    // ea gather + per-block partial histogram (LDS, no global atomics)
    __shared__ int   hd_[512];
    __shared__ float hf_[512];
    int k = b-579;
    hd_[tid]=0; hd_[256+tid]=0; hf_[tid]=0.f; hf_[256+tid]=0.f;
    __syncthreads();
    int e = k*256 + tid;
    int r = eidx[e], c = eidx[NEDGE+e];
    float a = markov[r*NNODE + c];
    ws[WS_EA+e] = a;
    atomicAdd(&hd_[c], 1);
    atomicAdd(&hf_[c], a);
    __syncthreads();
    ((int*)(ws+WS_DEGP))[k*512+tid]     = hd_[tid];
    ((int*)(ws+WS_DEGP))[k*512+256+tid] = hd_[256+tid];
    ws[WS_LSUMP + k*512+tid]     = hf_[tid];
    ws[WS_LSUMP + k*512+256+tid] = hf_[256+tid];
  } else if (b < 659){
    int j = b-643;
    const float* att = (j<8) ? g2as : g2ad;
    int h = j&7;
    float s = 0.f;
    for (int c=0;c<32;c++) s += att[h*32+c] * g2W[(h*32+c)*256 + tid];
    ws[WS_PS + j*256 + tid] = s;
  } else if (b < 675){
    __shared__ float T[64][65];
    int tb = b-659, tr = tb>>2, tc = tb&3;
    int w = tid>>6, c = tid&63;
    for (int k=0;k<16;k++){
      int r = k*4 + w;
      T[r][c] = g2W[(tr*64+r)*256 + tc*64 + c];
    }
    __syncthreads();
    for (int k=0;k<16;k++){
      int r = k*4 + w;
      ws[WS_G2WT + (tc*64+r)*256 + tr*64 + c] = T[c][r];
    }
  } else if (b == 675){
    ((int*)(ws+WS_CURSOR))[tid] = 0;
    ((int*)(ws+WS_CURSOR))[256+tid] = 0;
  } else if (b < 740){
    // Wc2 -> bf16 pack (input-only)
    int blk = b - 676;
    const float4* src = (const float4*)(Wc2 + blk*4096);
    ushort4* dst = (ushort4*)((unsigned short*)(ws+WS_WC2B) + blk*4096);
    #pragma unroll
    for (int i=0;i<4;i++){
      float4 v = src[i*256+tid];
      ushort4 u;
      u.x = f2bfbits(v.x); u.y = f2bfbits(v.y);
      u.z = f2bfbits(v.z); u.w = f2bfbits(v.w);
      dst[i*256+tid] = u;
    }
  } else {
    // zero-init OUT1F + out (split-K atomic accumulators; ws/out poisoned)
    int blk = b - 740;
    float4 z = {0.f,0.f,0.f,0.f};
    float4* o1f = (float4*)(ws + WS_OUT1F);
    float4* op  = (float4*)outp;
    o1f[blk*512 + tid] = z;
    o1f[blk*512 + 256 + tid] = z;
    op[blk*512 + tid] = z;
    op[blk*512 + 256 + tid] = z;
  }
}

// ===== K2: scan + scatter — wave-shuffle scan (2 barriers) ==================
__global__ __launch_bounds__(512)
void k_scansc(const int* __restrict__ eidx, float* ws){
  __shared__ int startS[512];
  __shared__ int wsum[8];
  int t = threadIdx.x, b = blockIdx.x, lane = t&63, w = t>>6;
  const int* dp = (const int*)(ws+WS_DEGP);
  int d = 0;
  #pragma unroll 8
  for (int k=0;k<64;k++) d += dp[k*512+t];
  int v = d;
  for (int off=1; off<64; off<<=1){
    int u = __shfl_up(v, off, 64);
    if (lane >= off) v += u;
  }
  if (lane==63) wsum[w] = v;
  __syncthreads();
  int base = 0;
  for (int k=0;k<w;k++) base += wsum[k];
  int incl = base + v;
  startS[t] = incl - d;
  if (b == 0){
    float l = 0.f;
    for (int k=0;k<64;k++) l += ws[WS_LSUMP+k*512+t];
    ((int*)(ws+WS_STARTS))[t] = incl - d;
    ((int*)(ws+WS_DEG))[t] = d;
    ws[WS_LATTR+t] = l / (float)(d>1 ? d : 1);
    if (t < 64){
      float mn = ws[WS_MMP+t], mx = ws[WS_MMP+64+t];
      for (int off=32; off; off>>=1){
        mn = fminf(mn, __shfl_down(mn,off,64));
        mx = fmaxf(mx, __shfl_down(mx,off,64));
      }
      if (t==0){ ws[WS_MM]=mn; ws[WS_MM+1]=mx; }
    }
  }
  __syncthreads();
  int e = b*512 + t;
  int c = eidx[NEDGE+e];
  int p = startS[c] + atomicAdd((int*)(ws+WS_CURSOR)+c, 1);
  ((int*)(ws+WS_CSRC))[p] = eidx[e];
  ws[WS_CEA+p] = ws[WS_EA+e];
}

// ============ GAT aggregate: CSR edges, single-pass softmax =================
// MODE1: rank-1 layer — per-head scalar aggregation of demand, X1 row in LDS,
//        then H2 = X1@W2T GEMV + PS projections (at 512-block occupancy).
// MODE2: aggregate H2 rows, +b2/relu, WESF GEMV, APACK pack (R3 structure).
template<int MODE>
__global__ __launch_bounds__(256)
void k_agg(const float* __restrict__ hbuf, const float* __restrict__ asrc,
           const float* __restrict__ adst, const float* __restrict__ AEp,
           const float* __restrict__ bvec, const float* __restrict__ demand,
           const float* __restrict__ w1,
           const float* __restrict__ dist, const float* __restrict__ markov,
           float* ws){
  int t = blockIdx.x, tid = threadIdx.x, hd = tid>>5;
  __shared__ int   srcE[256];
  __shared__ float eaE[256];
  __shared__ float demE[256];
  __shared__ float Lall[256*8];
  __shared__ float AE[8], mh[8], dh[8], sw[8], sagg[8];
  __shared__ float xrow[256], uvrow[64];
  if (tid<8) AE[tid]=AEp[tid];
  __syncthreads();
  const int* csrc = (const int*)(ws+WS_CSRC);
  const float* cea = ws+WS_CEA;
  int d  = ((const int*)(ws+WS_DEG))[t];
  int s0 = ((const int*)(ws+WS_STARTS))[t];
  if (d > 256) d = 256;
  for (int e=tid; e<d; e+=256){
    int s = csrc[s0+e];
    srcE[e]=s; eaE[e]=cea[s0+e];
    if (MODE==1) demE[e]=demand[s];
  }
  __syncthreads();
  {
    int h8 = tid&7;
    float adt = adst[t*8+h8], aeh = AE[h8];
    for (int e = tid>>3; e < d; e += 32){
      float a = asrc[srcE[e]*8+h8] + adt + eaE[e]*aeh;
      Lall[e*8+h8] = a>=0.f ? a : 0.2f*a;
    }
  }
  __syncthreads();
  {
    int h = tid>>5, j = tid&31;
    float aself = asrc[t*8+h] + adst[t*8+h] + ws[WS_LATTR+t]*AE[h];
    aself = aself>=0.f ? aself : 0.2f*aself;
    float mm = aself;
    for (int e=j; e<d; e+=32) mm = fmaxf(mm, Lall[e*8+h]);
    for (int off=16; off; off>>=1) mm = fmaxf(mm, __shfl_down(mm,off,32));
    mm = __shfl(mm, 0, 32);
    float dd = 0.f;
    for (int e=j; e<d; e+=32) dd += __expf(Lall[e*8+h]-mm);
    for (int off=16; off; off>>=1) dd += __shfl_down(dd,off,32);
    if (j==0){
      float se = __expf(aself-mm);
      mh[h]=mm; dh[h]=dd+se+1e-16f; sw[h]=se;
    }
  }
  __syncthreads();
  {
    int h8 = tid&7;
    for (int e = tid>>3; e < d; e += 32)
      Lall[e*8+h8] = __expf(Lall[e*8+h8] - mh[h8]);
  }
  __syncthreads();
  if (MODE == 1){
    // per-head scalar aggregation of demand (exact: h = demand*w1)
    int h = tid>>5, j = tid&31;
    float s = 0.f;
    for (int e=j; e<d; e+=32) s += Lall[e*8+h]*demE[e];
    for (int off=16; off; off>>=1) s += __shfl_down(s,off,32);
    if (j==0) sagg[h] = (s + sw[h]*demand[t]) / dh[h];
    __syncthreads();
    float v = fmaxf(sagg[hd]*w1[tid] + bvec[tid], 0.f);   // X1 row
    xrow[tid] = v;
    __syncthreads();
    // H2 = X1 @ W2^T (table GEMV at full 512-block occupancy)
    const float* g2wt = ws + WS_G2WT;
    float h0=0.f,h1=0.f,h2=0.f,h3=0.f;
    for (int c=0;c<256;c+=4){
      h0 += xrow[c+0]*g2wt[(c+0)*256+tid];
      h1 += xrow[c+1]*g2wt[(c+1)*256+tid];
      h2 += xrow[c+2]*g2wt[(c+2)*256+tid];
      h3 += xrow[c+3]*g2wt[(c+3)*256+tid];
    }
    ws[WS_H2 + t*256 + tid] = (h0+h1)+(h2+h3);
    if (tid < 64){
      int j2 = tid>>2, q = tid&3;
      const float* pr = ws + WS_PS + j2*256 + q*64;
      const float* xr = xrow + q*64;
      float p = 0.f;
      for (int c=0;c<64;c++) p += xr[c]*pr[c];
      p += __shfl_down(p,2,4);
      p += __shfl_down(p,1,4);
      if (q==0){
        if (j2<8) ws[WS_ASRC2 + t*8+j2] = p;
        else      ws[WS_ADST2 + t*8+(j2-8)] = p;
      }
    }
  } else {
    // aggregate H2 rows (8-way ILP), +b2/relu
    float a0 = sw[hd]*hbuf[t*256+tid], a1=0.f, a2=0.f, a3=0.f, a4=0.f, a5=0.f, a6=0.f, a7=0.f;
    int e = 0;
    for (; e+8<=d; e+=8){
      a0 += Lall[(e+0)*8+hd]*hbuf[srcE[e+0]*256+tid];
      a1 += Lall[(e+1)*8+hd]*hbuf[srcE[e+1]*256+tid];
      a2 += Lall[(e+2)*8+hd]*hbuf[srcE[e+2]*256+tid];
      a3 += Lall[(e+3)*8+hd]*hbuf[srcE[e+3]*256+tid];
      a4 += Lall[(e+4)*8+hd]*hbuf[srcE[e+4]*256+tid];
      a5 += Lall[(e+5)*8+hd]*hbuf[srcE[e+5]*256+tid];
      a6 += Lall[(e+6)*8+hd]*hbuf[srcE[e+6]*256+tid];
      a7 += Lall[(e+7)*8+hd]*hbuf[srcE[e+7]*256+tid];
    }
    for (; e<d; e++) a0 += Lall[e*8+hd]*hbuf[srcE[e]*256+tid];
    float v = fmaxf((((a0+a1)+(a2+a3))+((a4+a5)+(a6+a7)))/dh[hd] + bvec[tid], 0.f);
    xrow[tid] = v;
    __syncthreads();
    int k = tid>>2, q = tid&3;
    const float* wr = ws + WS_WESF + k*256 + q*64;
    const float* xr = xrow + q*64;
    float p = 0.f;
    for (int c=0;c<64;c++) p += xr[c]*wr[c];
    p += __shfl_down(p,2,4);
    p += __shfl_down(p,1,4);
    if (q==0){ ws[WS_UV + t*64+k] = p; uvrow[k] = p; }
    __syncthreads();
    float mn = ws[WS_MM], mx = ws[WS_MM+1];
    float inv = 1.0f/(mx-mn);
    bf16* ap = (bf16*)(ws+WS_APACK);
    const float* mrow = markov + t*512;
    for (int j=tid; j<K1P; j+=256){
      float v2;
      if (j<32)        v2 = uvrow[j];
      else if (j<544)  v2 = (dist[t*512 + j-32] - mn) * inv;
      else if (j<1056) v2 = mrow[j-544];
      else             v2 = 0.f;   // zero-pad (ws is poisoned)
      ap[(size_t)t*K1P + j] = __float2bfloat16(v2);
    }
  }
}

// ====== K5: sk+packB — 1024 thr, wave-shuffle reductions (2 barriers) =======
__global__ __launch_bounds__(1024)
void k_skpack(const float* __restrict__ Wc1, const float* __restrict__ bc1,
              const float* __restrict__ bes, const float* __restrict__ Wweek,
              const float* __restrict__ Wcap, const float* __restrict__ Wveh,
              const int* __restrict__ wd, const int* __restrict__ vh,
              const int* __restrict__ cp, float* ws){
  int o = blockIdx.x, tid = threadIdx.x;
  __shared__ float besf[32];
  __shared__ float red[512];
  __shared__ float red2[16];
  if (tid<32) besf[tid] = bes[tid];
  __syncthreads();
  const float* wr = Wc1 + (size_t)o*INLEN;
  bf16* bp  = (bf16*)(ws+WS_BPACK);
  float be = besf[tid&31];
  const float* uvp = ws + WS_UV + ((tid>>5)<<6) + 32 + (tid&31);
  float sP = 0.f, tP0=0.f, tP1=0.f, tP2=0.f, tP3=0.f;
  #pragma unroll
  for (int i=0;i<16;i+=4){
    float w0 = wr[tid + 1024*(i+0)];
    float w1 = wr[tid + 1024*(i+1)];
    float w2 = wr[tid + 1024*(i+2)];
    float w3 = wr[tid + 1024*(i+3)];
    float u0 = uvp[2048*(i+0)];
    float u1 = uvp[2048*(i+1)];
    float u2 = uvp[2048*(i+2)];
    float u3 = uvp[2048*(i+3)];
    sP += (w0+w1)+(w2+w3);
    tP0 += w0*(u0+be);
    tP1 += w1*(u1+be);
    tP2 += w2*(u2+be);
    tP3 += w3*(u3+be);
  }
  float tP = (tP0+tP1)+(tP2+tP3);
  if (tid < 512) tP += ws[WS_STOPV+tid] * wr[17417+tid];
  if (tid < 9){
    int g = tid/3, f = tid-g*3;
    float sv = (g==0) ? Wweek[wd[0]*3+f]
             : (g==1) ? Wcap[cp[0]*3+f]
                      : Wveh[vh[0]*3+f];
    tP += sv * wr[17408+tid];
  }
  int lane = tid&63, w = tid>>6;
  sP += __shfl_down(sP, 32, 64);
  if (lane < 32) red[w*32 + lane] = sP;
  for (int off=32; off; off>>=1) tP += __shfl_down(tP, off, 64);
  if (lane == 0) red2[w] = tP;
  __syncthreads();
  if (tid < 32){
    float s = 0.f;
    #pragma unroll
    for (int k=0;k<16;k++) s += red[k*32+tid];
    bp[(size_t)o*K1P + tid] = __float2bfloat16(s);
    bp[(size_t)o*K1P + 1056 + tid] = __float2bfloat16(0.f);  // zero-pad
  } else if (tid == 32){
    float s = 0.f;
    #pragma unroll
    for (int k=0;k<16;k++) s += red2[k];
    ws[WS_K+o] = s + bc1[o];
  }
  bp[(size_t)o*K1P + 32 + tid] = __float2bfloat16(wr[16384+tid]);
}

// == split-K bf16 MFMA GEMM: 64x64 tile, BK=64, 8 waves, f32 atomic output ===
template<bool ADDB>
__global__ __launch_bounds__(512)
void gemm_split(const bf16* __restrict__ A, const bf16* __restrict__ B,
                const float* __restrict__ bias, float* __restrict__ C,
                int N, int K){
  __shared__ short Als[2][4096];
  __shared__ short Bls[2][4096];
  const int tid = threadIdx.x;
  const int bm = blockIdx.y*64, bn = blockIdx.x*64;
  const int kz = blockIdx.z, NS = gridDim.z;
  const int nkT = K>>6;
  const int kb = (nkT*kz)/NS, ke = (nkT*(kz+1))/NS, cnt = ke-kb;
  const int wave = tid>>6, lane = tid&63;
  const int wm = wave>>2, wn = wave&3;
  const int r = lane&15, q = lane>>4;
  f32x4 acc[2] = {};
  const int lrow = tid>>3, lk8 = tid&7;
  const bf16* Ag = A + (size_t)(bm+lrow)*K + kb*64 + lk8*8;
  const bf16* Bg = B + (size_t)(bn+lrow)*K + kb*64 + lk8*8;
  const int sidx = ((lk8>>2)*256 + (lk8&3)*64 + lrow)*8;
  float4 av = *(const float4*)(Ag);
  float4 bv = *(const float4*)(Bg);
  *(float4*)(&Als[0][sidx]) = av;
  *(float4*)(&Bls[0][sidx]) = bv;
  __syncthreads();
  for (int kk=0; kk<cnt; kk++){
    int cur = kk&1, nxt = cur^1;
    if (kk+1 < cnt){
      av = *(const float4*)(Ag + (kk+1)*64);
      bv = *(const float4*)(Bg + (kk+1)*64);
    }
    #pragma unroll
    for (int k2=0; k2<2; k2++){
      bf16x8 bfr = *(const bf16x8*)(&Bls[cur][(k2*256 + q*64 + wn*16 + r)*8]);
      #pragma unroll
      for (int i=0;i<2;i++){
        bf16x8 af = *(const bf16x8*)(&Als[cur][(k2*256 + q*64 + wm*32 + i*16 + r)*8]);
        acc[i] = __builtin_amdgcn_mfma_f32_16x16x32_bf16(af, bfr, acc[i], 0,0,0);
      }
    }
    if (kk+1 < cnt){
      __syncthreads();
      *(float4*)(&Als[nxt][sidx]) = av;
      *(float4*)(&Bls[nxt][sidx]) = bv;
      __syncthreads();
    }
  }
  const int col = bn + wn*16 + r;
  const float bi = (ADDB && kz==0) ? bias[col] : 0.f;
  #pragma unroll
  for (int i=0;i<2;i++){
    int row = bm + wm*32 + i*16 + q*4;
    #pragma unroll
    for (int g=0; g<4; g++)
      atomicAdd(&C[(size_t)(row+g)*N + col], acc[i][g] + bi);
  }
}

// ====== ep1: OUT1F + K-bias -> relu -> bf16 OUT1 (128 blocks, trivial) ======
__global__ __launch_bounds__(256)
void k_ep1(float* ws){
  int idx = (blockIdx.x*256 + threadIdx.x)*8;
  const float4* s  = (const float4*)(ws + WS_OUT1F + idx);
  const float4* kv = (const float4*)(ws + WS_K + (idx&511));
  float4 v0 = s[0], v1 = s[1];
  float4 k0 = kv[0], k1 = kv[1];
  ushort4 u0, u1;
  u0.x = f2bfbits(fmaxf(v0.x+k0.x, 0.f));
  u0.y = f2bfbits(fmaxf(v0.y+k0.y, 0.f));
  u0.z = f2bfbits(fmaxf(v0.z+k0.z, 0.f));
  u0.w = f2bfbits(fmaxf(v0.w+k0.w, 0.f));
  u1.x = f2bfbits(fmaxf(v1.x+k1.x, 0.f));
  u1.y = f2bfbits(fmaxf(v1.y+k1.y, 0.f));
  u1.z = f2bfbits(fmaxf(v1.z+k1.z, 0.f));
  u1.w = f2bfbits(fmaxf(v1.w+k1.w, 0.f));
  ushort4* d = (ushort4*)((unsigned short*)(ws+WS_OUT1) + idx);
  d[0] = u0; d[1] = u1;
}

extern "C" void kernel_launch(void* const* d_in, const int* in_sizes, int n_in,
                              void* d_out, int out_size, void* d_ws, size_t ws_size,
                              hipStream_t stream){
  const float* dist   = (const float*)d_in[0];
  const float* markov = (const float*)d_in[1];
  const float* demand = (const float*)d_in[2];
  const float* Wweek  = (const float*)d_in[3];
  const float* Wcap   = (const float*)d_in[4];
  const float* Wveh   = (const float*)d_in[5];
  const float* g1W    = (const float*)d_in[6];
  const float* g1as   = (const float*)d_in[7];
  const float* g1ad   = (const float*)d_in[8];
  const float* g1We   = (const float*)d_in[9];
  const float* g1ae   = (const float*)d_in[10];
  const float* g1b    = (const float*)d_in[11];
  const float* g2W    = (const float*)d_in[12];
  const float* g2as   = (const float*)d_in[13];
  const float* g2ad   = (const float*)d_in[14];
  const float* g2We   = (const float*)d_in[15];
  const float* g2ae   = (const float*)d_in[16];
  const float* g2b    = (const float*)d_in[17];
  const float* Wes    = (const float*)d_in[18];
  const float* bes    = (const float*)d_in[19];
  const float* Wc1    = (const float*)d_in[20];
  const float* bc1    = (const float*)d_in[21];
  const float* Wc2    = (const float*)d_in[22];
  const float* bc2    = (const float*)d_in[23];
  const int*   stops  = (const int*)d_in[24];
  const int*   eidx   = (const int*)d_in[25];
  const int*   wd     = (const int*)d_in[26];
  const int*   vh     = (const int*)d_in[27];
  const int*   cp     = (const int*)d_in[28];
  float* out = (float*)d_out;
  float* ws = (float*)d_ws;

  k_prep<<<868,256,0,stream>>>(demand, g1W, g1as, g1ad, stops, Wes, dist, markov, eidx,
                               g1We, g1ae, g2We, g2ae, g2W, g2as, g2ad, Wc2, out, ws);
  k_scansc<<<32,512,0,stream>>>(eidx, ws);
  k_agg<1><<<512,256,0,stream>>>(nullptr, ws+WS_ASRC, ws+WS_ADST, ws+WS_AE, g1b,
                                 demand, g1W, dist, markov, ws);
  k_agg<2><<<512,256,0,stream>>>(ws+WS_H2, ws+WS_ASRC2, ws+WS_ADST2, ws+WS_AE+8, g2b,
                                 demand, g1W, dist, markov, ws);
  k_skpack<<<512,1024,0,stream>>>(Wc1, bc1, bes, Wweek, Wcap, Wveh, wd, vh, cp, ws);
  gemm_split<false><<<dim3(8,8,4),512,0,stream>>>((const bf16*)(ws+WS_APACK), (const bf16*)(ws+WS_BPACK),
                                                  nullptr, ws+WS_OUT1F, 512, K1P);
  k_ep1<<<128,256,0,stream>>>(ws);
  gemm_split<true><<<dim3(8,8,2),512,0,stream>>>((const bf16*)(ws+WS_OUT1), (const bf16*)(ws+WS_WC2B),
                                                 bc2, out, 512, 512);
}